// Round 2
// baseline (788.277 us; speedup 1.0000x reference)
//
#include <hip/hip_runtime.h>
#include <math.h>

// Problem constants (MultiHeadAttention: B=2, L=2048, D=768, H=12, HD=64)
#define B_  2
#define L_  2048
#define D_  768
#define H_  12
#define HD_ 64
#define M_  (B_*L_)          // 4096 rows for the GEMMs
#define N3_ (3*D_)           // 2304
#define OUT_ELEMS ((size_t)B_*L_*D_)   // 3145728

static constexpr float kScale = 0.022097086912079608f;  // 1/sqrt(2048) (ref divides by sqrt(L))
static constexpr float kLog2_10000_div32 = 0.415241011860920f;

typedef __attribute__((ext_vector_type(8))) short short8;
typedef __attribute__((ext_vector_type(4))) float f32x4;

__device__ __forceinline__ unsigned short f2bf(float f) {
  union { float f; unsigned u; } v; v.f = f;
  unsigned r = v.u + 0x7FFFu + ((v.u >> 16) & 1u);   // round-to-nearest-even
  return (unsigned short)(r >> 16);
}

__device__ __forceinline__ void async_cp16(const void* g, void* l) {
  __builtin_amdgcn_global_load_lds((const __attribute__((address_space(1))) void*)g,
                                   (__attribute__((address_space(3))) void*)l, 16, 0, 0);
}

// ===================== convert fp32 -> bf16 (straight) =====================
__global__ __launch_bounds__(256) void bf16conv_kernel(const float* __restrict__ in,
                                                       unsigned short* __restrict__ out)
{
  const int idx = blockIdx.x * 256 + threadIdx.x;
  const float* src = in + (size_t)idx * 8;
  float4 a = *(const float4*)src;
  float4 b = *(const float4*)(src + 4);
  unsigned short t[8];
  t[0] = f2bf(a.x); t[1] = f2bf(a.y); t[2] = f2bf(a.z); t[3] = f2bf(a.w);
  t[4] = f2bf(b.x); t[5] = f2bf(b.y); t[6] = f2bf(b.z); t[7] = f2bf(b.w);
  *(uint4*)(out + (size_t)idx * 8) = *(uint4*)t;
}

// ===================== weight transpose+convert: fp32 [K][N] -> bf16 [N][K] =====================
__global__ __launch_bounds__(256) void wtrans_kernel(const float* __restrict__ in,
                                                     unsigned short* __restrict__ out,
                                                     int K, int N)
{
  __shared__ __align__(16) unsigned short T[64][72];
  const int n0 = blockIdx.x * 64;
  const int k0 = blockIdx.y * 64;
  const int tid = threadIdx.x;
  const int row = tid >> 2;          // 0..63
  const int col = (tid & 3) * 16;    // 0,16,32,48
  {
    const float* src = in + (size_t)(k0 + row) * N + n0 + col;
    unsigned short tmp[16];
#pragma unroll
    for (int j = 0; j < 16; j += 4) {
      float4 v = *(const float4*)(src + j);
      tmp[j] = f2bf(v.x); tmp[j + 1] = f2bf(v.y); tmp[j + 2] = f2bf(v.z); tmp[j + 3] = f2bf(v.w);
    }
    *(uint4*)&T[row][col]     = *(uint4*)tmp;       // T[k][n]
    *(uint4*)&T[row][col + 8] = *(uint4*)(tmp + 8);
  }
  __syncthreads();
  unsigned short tmp[16];
#pragma unroll
  for (int j = 0; j < 16; ++j) tmp[j] = T[col + j][row];   // gather k-run for fixed n=row
  unsigned short* dst = out + (size_t)(n0 + row) * K + k0 + col;
  *(uint4*)dst       = *(uint4*)tmp;
  *(uint4*)(dst + 8) = *(uint4*)(tmp + 8);
}

// ===================== V transpose bf16: [B,H,L,64] -> [B,H,64,L] =====================
__global__ __launch_bounds__(256) void vtrans_kernel(const unsigned short* __restrict__ vb,
                                                     unsigned short* __restrict__ vt)
{
  __shared__ __align__(16) unsigned short T[64][72];
  const int bh = blockIdx.y;
  const int l0 = blockIdx.x * 64;
  const int tid = threadIdx.x;
  const int row = tid >> 2;
  const int col = (tid & 3) * 16;
  {
    const unsigned short* src = vb + ((size_t)bh * L_ + l0 + row) * HD_ + col;
    *(uint4*)&T[row][col]     = *(const uint4*)src;        // T[l][d]
    *(uint4*)&T[row][col + 8] = *(const uint4*)(src + 8);
  }
  __syncthreads();
  unsigned short tmp[16];
#pragma unroll
  for (int j = 0; j < 16; ++j) tmp[j] = T[col + j][row];   // l-run for fixed d=row
  unsigned short* dst = vt + ((size_t)bh * HD_ + row) * L_ + l0 + col;
  *(uint4*)dst       = *(uint4*)tmp;
  *(uint4*)(dst + 8) = *(uint4*)(tmp + 8);
}

// ===================== bf16 MFMA GEMM: C[M][N] = A[M][K] * Bt[N][K]^T + bias =====================
// 128x128 tile, BK=32, 4 waves each computing a 64x64 quadrant (4x4 of 16x16x32 mfma).
// Staging via global_load_lds(16B) with chunk^=(row&3) XOR swizzle (conflict-free ds_read_b128).
// mode 0: fp32 C store.  mode 1: QKV -> bf16 q/k/v head-split with FUSED RoPE on q,k.
__global__ __launch_bounds__(256) void gemm_mfma_kernel(
    const unsigned short* __restrict__ A, const unsigned short* __restrict__ Bt,
    const float* __restrict__ bias, float* __restrict__ C,
    int M, int N, int K, int mode,
    unsigned short* __restrict__ qp, unsigned short* __restrict__ kp,
    unsigned short* __restrict__ vp)
{
  __shared__ __align__(16) unsigned short As[128 * 32];
  __shared__ __align__(16) unsigned short Bs[128 * 32];

  const int tid  = threadIdx.x;
  const int w    = tid >> 6;
  const int lane = tid & 63;
  const int m16  = lane & 15;
  const int quad = lane >> 4;
  const int wr   = w & 1;        // row half of quadrant
  const int wc   = w >> 1;       // col half

  const int bm = blockIdx.y * 128;
  const int bn = blockIdx.x * 128;

  // staging: wave w covers slots [w*128, w*128+128); slot s -> row s/4, stored chunk s%4,
  // fetched data chunk (s%4)^(row&3)
  const int s0 = w * 128 + lane;
  const int s1 = s0 + 64;
  const int r0 = s0 >> 2, c0 = (s0 & 3) ^ (r0 & 3);
  const int r1 = s1 >> 2, c1 = (s1 & 3) ^ (r1 & 3);
  const unsigned short* gA0 = A + (size_t)(bm + r0) * K + c0 * 8;
  const unsigned short* gA1 = A + (size_t)(bm + r1) * K + c1 * 8;
  const unsigned short* gB0 = Bt + (size_t)(bn + r0) * K + c0 * 8;
  const unsigned short* gB1 = Bt + (size_t)(bn + r1) * K + c1 * 8;
  unsigned short* lA0 = As + (w * 128) * 8;
  unsigned short* lA1 = As + (w * 128 + 64) * 8;
  unsigned short* lB0 = Bs + (w * 128) * 8;
  unsigned short* lB1 = Bs + (w * 128 + 64) * 8;

  // fragment LDS addresses (k0-invariant): row r, chunk quad^(r&3)
  const int sw = quad ^ (m16 & 3);   // (r&3)==(m16&3) since tile bases are multiples of 16
  const short8* pA[4];
  const short8* pB[4];
#pragma unroll
  for (int i = 0; i < 4; ++i) {
    const int ra = wr * 64 + i * 16 + m16;
    const int rb = wc * 64 + i * 16 + m16;
    pA[i] = (const short8*)(As + ra * 32 + sw * 8);
    pB[i] = (const short8*)(Bs + rb * 32 + sw * 8);
  }

  f32x4 acc[4][4];
#pragma unroll
  for (int i = 0; i < 4; ++i)
#pragma unroll
    for (int j = 0; j < 4; ++j) { acc[i][j][0] = 0.f; acc[i][j][1] = 0.f; acc[i][j][2] = 0.f; acc[i][j][3] = 0.f; }

  for (int k0 = 0; k0 < K; k0 += 32) {
    async_cp16(gA0 + k0, lA0);
    async_cp16(gA1 + k0, lA1);
    async_cp16(gB0 + k0, lB0);
    async_cp16(gB1 + k0, lB1);
    __syncthreads();   // drains vmcnt: LDS staging complete
    short8 af[4], bfr[4];
#pragma unroll
    for (int i = 0; i < 4; ++i) { af[i] = *pA[i]; bfr[i] = *pB[i]; }
#pragma unroll
    for (int i = 0; i < 4; ++i)
#pragma unroll
      for (int j = 0; j < 4; ++j)
        acc[i][j] = __builtin_amdgcn_mfma_f32_16x16x32_bf16(af[i], bfr[j], acc[i][j], 0, 0, 0);
    __syncthreads();   // all reads done before next stage overwrites
  }

  if (mode == 0) {
#pragma unroll
    for (int j = 0; j < 4; ++j) {
      const int n = bn + wc * 64 + j * 16 + m16;
      const float bj = bias[n];
#pragma unroll
      for (int i = 0; i < 4; ++i) {
        const int mrow = bm + wr * 64 + i * 16 + quad * 4;
#pragma unroll
        for (int r2 = 0; r2 < 4; ++r2)
          C[(size_t)(mrow + r2) * N + n] = acc[i][j][r2] + bj;
      }
    }
  } else {
    // QKV epilogue: segment decode (wave-uniform: col base is 64-aligned, 768 % 64 == 0)
    const int segbase = bn + wc * 64;
    const int which = segbase / D_;
    const int h = (segbase - which * D_) >> 6;
    unsigned short* dstT = (which == 0) ? qp : (which == 1) ? kp : vp;
    float bj[4];
#pragma unroll
    for (int og = 0; og < 4; ++og) bj[og] = bias[segbase + og * 16 + m16];
    // RoPE inv freqs: d = og*16+m16, idx = d&31 -> m16 (og even) or 16+m16 (og odd)
    const float invfA = exp2f(-(float)m16 * kLog2_10000_div32);
    const float invfB = exp2f(-(float)(16 + m16) * kLog2_10000_div32);

#pragma unroll
    for (int i = 0; i < 4; ++i) {
      const int mrow = bm + wr * 64 + i * 16 + quad * 4;
#pragma unroll
      for (int r2 = 0; r2 < 4; ++r2) {
        const int m = mrow + r2;
        const int bi = m >> 11;
        const int li = m & (L_ - 1);
        float vals[4];
#pragma unroll
        for (int og = 0; og < 4; ++og) vals[og] = acc[i][og][r2] + bj[og];
        unsigned short* drow = dstT + (((size_t)(bi * H_ + h)) * L_ + li) * HD_;
        if (which == 2) {
#pragma unroll
          for (int og = 0; og < 4; ++og) drow[og * 16 + m16] = f2bf(vals[og]);
        } else {
          const float fl = (float)li;
#pragma unroll
          for (int og = 0; og < 4; ++og) {
            const int d = og * 16 + m16;
            const float theta = fl * ((og & 1) ? invfB : invfA);
            float sv, cv;
            __sincosf(theta, &sv, &cv);
            const float part = vals[og ^ 2];          // pre-rope partner at d^32
            const float rot = (og < 2) ? -part : part;  // rotate_half sign
            drow[d] = f2bf(vals[og] * cv + rot * sv);
          }
        }
      }
    }
  }
}

// ============================ Fused causal attention (MFMA bf16) ============================
// v2: BARRIER-FREE. K fragments are read directly from global (coalesced, L2-resident:
// 256KB/head). V is staged into per-wave-PRIVATE padded LDS (no cross-wave sync), with the
// next tile's V globals prefetched into registers during the current tile's compute.
// Probs stores are nontemporal; the masked-region zero-fill runs at the END so its store
// drain doesn't entangle with compute-phase vmcnt waits.
__global__ __launch_bounds__(256) void attn_mfma_kernel(
    const unsigned short* __restrict__ qb, const unsigned short* __restrict__ kb,
    const unsigned short* __restrict__ vt, float* __restrict__ probs,
    unsigned short* __restrict__ attnb)
{
  __shared__ __align__(16) unsigned short Vs[4][64][72];   // per-wave private [d][kpos]
  __shared__ __align__(16) unsigned short Pb[4][16][72];   // per-wave P tile

  const int tid  = threadIdx.x;
  const int w    = tid >> 6;
  const int lane = tid & 63;
  const int m16  = lane & 15;
  const int quad = lane >> 4;

  const int bh = blockIdx.y;
  const int qt = (int)gridDim.x - 1 - (int)blockIdx.x;   // big tiles first
  const int q0 = qt * 64;
  const int bb = bh / H_;
  const int hh = bh - bb * H_;
  const int ktiles = qt + 1;
  const int qrow_base = q0 + w * 16;

  const unsigned short* kbase = kb + (size_t)bh * L_ * HD_;
  const unsigned short* vbase = vt + (size_t)bh * HD_ * L_;

  // Q fragments (registers, reused across all k-tiles)
  const unsigned short* qp = qb + ((size_t)bh * L_ + qrow_base + m16) * HD_ + quad * 8;
  const short8 qf0 = *(const short8*)(qp);
  const short8 qf1 = *(const short8*)(qp + 32);

  // K fragment base: row cg*16+m16 of tile k0, col chunk quad (b0) / quad+4 (b1)
  const unsigned short* kfp = kbase + (size_t)m16 * HD_ + quad * 8;

  // ---------------- pass 1: row sums (pure streaming, no LDS, no barriers) ----------------
  float lsum[4] = {0.f, 0.f, 0.f, 0.f};
  for (int kt = 0; kt < ktiles; ++kt) {
    const int k0 = kt * 64;
    short8 kb0[4], kb1[4];
#pragma unroll
    for (int cg = 0; cg < 4; ++cg) {
      const unsigned short* kr = kfp + (size_t)(k0 + cg * 16) * HD_;
      kb0[cg] = *(const short8*)(kr);
      kb1[cg] = *(const short8*)(kr + 32);
    }
#pragma unroll
    for (int cg = 0; cg < 4; ++cg) {
      f32x4 s = {0.f, 0.f, 0.f, 0.f};
      s = __builtin_amdgcn_mfma_f32_16x16x32_bf16(qf0, kb0[cg], s, 0, 0, 0);
      s = __builtin_amdgcn_mfma_f32_16x16x32_bf16(qf1, kb1[cg], s, 0, 0, 0);
      const int kcol = k0 + cg * 16 + m16;
#pragma unroll
      for (int r2 = 0; r2 < 4; ++r2) {
        const int qrow = qrow_base + quad * 4 + r2;
        const float e = __expf(s[r2] * kScale);
        lsum[r2] += (kcol <= qrow) ? e : 0.f;
      }
    }
  }
  float linv[4];
#pragma unroll
  for (int r2 = 0; r2 < 4; ++r2) {
    float v = lsum[r2];
    v += __shfl_xor(v, 1, 64);
    v += __shfl_xor(v, 2, 64);
    v += __shfl_xor(v, 4, 64);
    v += __shfl_xor(v, 8, 64);
    linv[r2] = 1.f / v;
  }

  // ---------------- pass 2: probs + PV (per-wave private V staging, no barriers) ----------
  f32x4 oacc[4];
#pragma unroll
  for (int og = 0; og < 4; ++og) { oacc[og][0]=0.f; oacc[og][1]=0.f; oacc[og][2]=0.f; oacc[og][3]=0.f; }

  unsigned short* Vw = &Vs[w][0][0];
  const int vr = lane >> 2;            // 0..15
  const int vc = (lane & 3) * 16;      // 0,16,32,48 (shorts)
  const unsigned short* vsrc0 = vbase + (size_t)vr * L_ + vc;

  uint4 vstg[8];
  // prologue: load V tile 0 into registers
#pragma unroll
  for (int j = 0; j < 4; ++j) {
    const unsigned short* s = vsrc0 + (size_t)(16 * j) * L_;
    vstg[2 * j]     = *(const uint4*)s;
    vstg[2 * j + 1] = *(const uint4*)(s + 8);
  }

  for (int kt = 0; kt < ktiles; ++kt) {
    const int k0 = kt * 64;
    // write V(t) registers -> private padded LDS
#pragma unroll
    for (int j = 0; j < 4; ++j) {
      unsigned short* d = Vw + (vr + 16 * j) * 72 + vc;
      *(uint4*)d       = vstg[2 * j];
      *(uint4*)(d + 8) = vstg[2 * j + 1];
    }
    // issue K fragment loads for this tile
    short8 kb0[4], kb1[4];
#pragma unroll
    for (int cg = 0; cg < 4; ++cg) {
      const unsigned short* kr = kfp + (size_t)(k0 + cg * 16) * HD_;
      kb0[cg] = *(const short8*)(kr);
      kb1[cg] = *(const short8*)(kr + 32);
    }
    // prefetch V(t+1) globals (lands during QK^T/softmax/PV below)
    const int k0n = (kt + 1 < ktiles) ? k0 + 64 : k0;
#pragma unroll
    for (int j = 0; j < 4; ++j) {
      const unsigned short* s = vsrc0 + (size_t)(16 * j) * L_ + k0n;
      vstg[2 * j]     = *(const uint4*)s;
      vstg[2 * j + 1] = *(const uint4*)(s + 8);
    }
    // QK^T + normalize + probs store + P tile
#pragma unroll
    for (int cg = 0; cg < 4; ++cg) {
      f32x4 s = {0.f, 0.f, 0.f, 0.f};
      s = __builtin_amdgcn_mfma_f32_16x16x32_bf16(qf0, kb0[cg], s, 0, 0, 0);
      s = __builtin_amdgcn_mfma_f32_16x16x32_bf16(qf1, kb1[cg], s, 0, 0, 0);
      const int kcol = k0 + cg * 16 + m16;
#pragma unroll
      for (int r2 = 0; r2 < 4; ++r2) {
        const int qrow = qrow_base + quad * 4 + r2;
        const float p = (kcol <= qrow) ? __expf(s[r2] * kScale) * linv[r2] : 0.f;
        __builtin_nontemporal_store(p, &probs[((size_t)bh * L_ + qrow) * L_ + kcol]);
        Pb[w][quad * 4 + r2][cg * 16 + m16] = f2bf(p);
      }
    }
    // PV: A = P tile (via private LDS transpose), B = V^T fragments from private LDS
    const short8 pa0 = *(const short8*)&Pb[w][m16][quad * 8];
    const short8 pa1 = *(const short8*)&Pb[w][m16][32 + quad * 8];
#pragma unroll
    for (int og = 0; og < 4; ++og) {
      const short8 v0 = *(const short8*)(Vw + (og * 16 + m16) * 72 + quad * 8);
      const short8 v1 = *(const short8*)(Vw + (og * 16 + m16) * 72 + 32 + quad * 8);
      oacc[og] = __builtin_amdgcn_mfma_f32_16x16x32_bf16(pa0, v0, oacc[og], 0, 0, 0);
      oacc[og] = __builtin_amdgcn_mfma_f32_16x16x32_bf16(pa1, v1, oacc[og], 0, 0, 0);
    }
  }

  // O epilogue -> attn [B,L,D] bf16 (feeds out-proj GEMM directly)
#pragma unroll
  for (int og = 0; og < 4; ++og)
#pragma unroll
    for (int r2 = 0; r2 < 4; ++r2)
      attnb[((size_t)bb * L_ + qrow_base + quad * 4 + r2) * D_ + hh * HD_ + og * 16 + m16] =
          f2bf(oacc[og][r2]);

  // zero-fill masked probs columns beyond processed tiles (fire-and-forget at kernel end)
  {
    const f32x4 z4 = {0.f, 0.f, 0.f, 0.f};
#pragma unroll
    for (int r2 = 0; r2 < 4; ++r2) {
      float* pr = probs + ((size_t)bh * L_ + qrow_base + quad * 4 + r2) * L_;
      for (int c0 = ktiles * 64; c0 < L_; c0 += 64)
        __builtin_nontemporal_store(z4, (f32x4*)(pr + c0 + m16 * 4));
    }
  }
}

// ============================ launcher ============================
extern "C" void kernel_launch(void* const* d_in, const int* in_sizes, int n_in,
                              void* d_out, int out_size, void* d_ws, size_t ws_size,
                              hipStream_t stream)
{
  const float* x     = (const float*)d_in[0];
  const float* w_qkv = (const float*)d_in[1];
  const float* b_qkv = (const float*)d_in[2];
  const float* w_out = (const float*)d_in[3];
  const float* b_out = (const float*)d_in[4];

  float* out   = (float*)d_out;
  float* probs = out + OUT_ELEMS;

  const size_t NE = (size_t)B_ * H_ * L_ * HD_;   // 3145728
  unsigned short* qbw   = (unsigned short*)d_ws;  // bf16 q [B,H,L,64]
  unsigned short* kbw   = qbw + NE;
  unsigned short* vbw   = kbw + NE;
  unsigned short* vtw   = vbw + NE;               // v^T [B,H,64,L]
  unsigned short* xbw   = vtw + NE;               // bf16 x [M,K]
  unsigned short* attnb = xbw + NE;               // bf16 attn [B,L,D]
  unsigned short* wqT   = attnb + NE;             // bf16 w_qkv^T [2304,768]
  unsigned short* woT   = wqT + (size_t)N3_ * D_; // bf16 w_out^T [768,768]
  // total: 6*6.29MB + 3.54MB + 1.18MB = 42.5 MB

  // 1) conversions (independent)
  bf16conv_kernel<<<(int)(OUT_ELEMS / 8 / 256), 256, 0, stream>>>(x, xbw);
  wtrans_kernel<<<dim3(N3_ / 64, D_ / 64), 256, 0, stream>>>(w_qkv, wqT, D_, N3_);
  wtrans_kernel<<<dim3(D_ / 64, D_ / 64), 256, 0, stream>>>(w_out, woT, D_, D_);

  // 2) QKV projection (MFMA) + bias + fused RoPE + head-split -> bf16 q/k/v
  gemm_mfma_kernel<<<dim3(N3_ / 128, M_ / 128), 256, 0, stream>>>(
      xbw, wqT, b_qkv, nullptr, M_, N3_, D_, 1, qbw, kbw, vbw);

  // 3) V transpose for PV B-operand
  vtrans_kernel<<<dim3(L_ / 64, B_ * H_), 256, 0, stream>>>(vbw, vtw);

  // 4) fused causal attention: probs + attn (bf16)
  attn_mfma_kernel<<<dim3(L_ / 64, B_ * H_), 256, 0, stream>>>(qbw, kbw, vtw, probs, attnb);

  // 5) output projection (MFMA) + bias -> fp32 out
  gemm_mfma_kernel<<<dim3(D_ / 128, M_ / 128), 256, 0, stream>>>(
      attnb, woT, b_out, out, M_, D_, D_, 0, nullptr, nullptr, nullptr);
}

// Round 4
// 620.860 us; speedup vs baseline: 1.2697x; 1.2697x over previous
//
#include <hip/hip_runtime.h>
#include <math.h>

// Problem constants (MultiHeadAttention: B=2, L=2048, D=768, H=12, HD=64)
#define B_  2
#define L_  2048
#define D_  768
#define H_  12
#define HD_ 64
#define M_  (B_*L_)          // 4096 rows for the GEMMs
#define N3_ (3*D_)           // 2304
#define OUT_ELEMS ((size_t)B_*L_*D_)   // 3145728

static constexpr float kScale = 0.022097086912079608f;  // 1/sqrt(2048) (ref divides by sqrt(L))
static constexpr float kLog2_10000_div32 = 0.415241011860920f;

typedef __attribute__((ext_vector_type(8))) short short8;
typedef __attribute__((ext_vector_type(4))) float f32x4;

__device__ __forceinline__ unsigned short f2bf(float f) {
  union { float f; unsigned u; } v; v.f = f;
  unsigned r = v.u + 0x7FFFu + ((v.u >> 16) & 1u);   // round-to-nearest-even
  return (unsigned short)(r >> 16);
}

__device__ __forceinline__ void async_cp16(const void* g, void* l) {
  __builtin_amdgcn_global_load_lds((const __attribute__((address_space(1))) void*)g,
                                   (__attribute__((address_space(3))) void*)l, 16, 0, 0);
}

// ===================== convert fp32 -> bf16 (straight) =====================
__global__ __launch_bounds__(256) void bf16conv_kernel(const float* __restrict__ in,
                                                       unsigned short* __restrict__ out)
{
  const int idx = blockIdx.x * 256 + threadIdx.x;
  const float* src = in + (size_t)idx * 8;
  float4 a = *(const float4*)src;
  float4 b = *(const float4*)(src + 4);
  unsigned short t[8];
  t[0] = f2bf(a.x); t[1] = f2bf(a.y); t[2] = f2bf(a.z); t[3] = f2bf(a.w);
  t[4] = f2bf(b.x); t[5] = f2bf(b.y); t[6] = f2bf(b.z); t[7] = f2bf(b.w);
  *(uint4*)(out + (size_t)idx * 8) = *(uint4*)t;
}

// ===================== weight transpose+convert: fp32 [K][N] -> bf16 [N][K] =====================
__global__ __launch_bounds__(256) void wtrans_kernel(const float* __restrict__ in,
                                                     unsigned short* __restrict__ out,
                                                     int K, int N)
{
  __shared__ __align__(16) unsigned short T[64][72];
  const int n0 = blockIdx.x * 64;
  const int k0 = blockIdx.y * 64;
  const int tid = threadIdx.x;
  const int row = tid >> 2;          // 0..63
  const int col = (tid & 3) * 16;    // 0,16,32,48
  {
    const float* src = in + (size_t)(k0 + row) * N + n0 + col;
    unsigned short tmp[16];
#pragma unroll
    for (int j = 0; j < 16; j += 4) {
      float4 v = *(const float4*)(src + j);
      tmp[j] = f2bf(v.x); tmp[j + 1] = f2bf(v.y); tmp[j + 2] = f2bf(v.z); tmp[j + 3] = f2bf(v.w);
    }
    *(uint4*)&T[row][col]     = *(uint4*)tmp;       // T[k][n]
    *(uint4*)&T[row][col + 8] = *(uint4*)(tmp + 8);
  }
  __syncthreads();
  unsigned short tmp[16];
#pragma unroll
  for (int j = 0; j < 16; ++j) tmp[j] = T[col + j][row];   // gather k-run for fixed n=row
  unsigned short* dst = out + (size_t)(n0 + row) * K + k0 + col;
  *(uint4*)dst       = *(uint4*)tmp;
  *(uint4*)(dst + 8) = *(uint4*)(tmp + 8);
}

// ===================== V transpose bf16: [B,H,L,64] -> [B,H,64,L] =====================
__global__ __launch_bounds__(256) void vtrans_kernel(const unsigned short* __restrict__ vb,
                                                     unsigned short* __restrict__ vt)
{
  __shared__ __align__(16) unsigned short T[64][72];
  const int bh = blockIdx.y;
  const int l0 = blockIdx.x * 64;
  const int tid = threadIdx.x;
  const int row = tid >> 2;
  const int col = (tid & 3) * 16;
  {
    const unsigned short* src = vb + ((size_t)bh * L_ + l0 + row) * HD_ + col;
    *(uint4*)&T[row][col]     = *(const uint4*)src;        // T[l][d]
    *(uint4*)&T[row][col + 8] = *(const uint4*)(src + 8);
  }
  __syncthreads();
  unsigned short tmp[16];
#pragma unroll
  for (int j = 0; j < 16; ++j) tmp[j] = T[col + j][row];   // l-run for fixed d=row
  unsigned short* dst = vt + ((size_t)bh * HD_ + row) * L_ + l0 + col;
  *(uint4*)dst       = *(uint4*)tmp;
  *(uint4*)(dst + 8) = *(uint4*)(tmp + 8);
}

// ===================== bf16 MFMA GEMM: C[M][N] = A[M][K] * Bt[N][K]^T + bias =====================
// 128x128 tile, BK=32, 4 waves each computing a 64x64 quadrant (4x4 of 16x16x32 mfma).
// v3: DOUBLE-BUFFERED async staging (T3 minimum): stage k0+32 into buf^1 BEFORE computing
// buf, ONE __syncthreads per K-step (drains the prefetch after compute has hidden its
// latency). Staging via global_load_lds(16B) with chunk^=(row&3) XOR swizzle.
// mode 0: fp32 C store.  mode 1: QKV -> bf16 q/k/v head-split with FUSED RoPE on q,k.
__global__ __launch_bounds__(256) void gemm_mfma_kernel(
    const unsigned short* __restrict__ A, const unsigned short* __restrict__ Bt,
    const float* __restrict__ bias, float* __restrict__ C,
    int M, int N, int K, int mode,
    unsigned short* __restrict__ qp, unsigned short* __restrict__ kp,
    unsigned short* __restrict__ vp)
{
  __shared__ __align__(16) unsigned short As[2][128 * 32];
  __shared__ __align__(16) unsigned short Bs[2][128 * 32];

  const int tid  = threadIdx.x;
  const int w    = tid >> 6;
  const int lane = tid & 63;
  const int m16  = lane & 15;
  const int quad = lane >> 4;
  const int wr   = w & 1;        // row half of quadrant
  const int wc   = w >> 1;       // col half

  const int bm = blockIdx.y * 128;
  const int bn = blockIdx.x * 128;

  // staging: wave w covers slots [w*128, w*128+128); slot s -> row s/4, stored chunk s%4,
  // fetched data chunk (s%4)^(row&3)
  const int s0 = w * 128 + lane;
  const int s1 = s0 + 64;
  const int r0 = s0 >> 2, c0 = (s0 & 3) ^ (r0 & 3);
  const int r1 = s1 >> 2, c1 = (s1 & 3) ^ (r1 & 3);
  const unsigned short* gA0 = A + (size_t)(bm + r0) * K + c0 * 8;
  const unsigned short* gA1 = A + (size_t)(bm + r1) * K + c1 * 8;
  const unsigned short* gB0 = Bt + (size_t)(bn + r0) * K + c0 * 8;
  const unsigned short* gB1 = Bt + (size_t)(bn + r1) * K + c1 * 8;
  const int oS0 = (w * 128) * 8;        // LDS short-offset for call 0 (wave-uniform)
  const int oS1 = (w * 128 + 64) * 8;   // call 1

  // fragment LDS offsets (k0-invariant): row r, chunk quad^(r&3)
  const int sw = quad ^ (m16 & 3);   // (r&3)==(m16&3) since tile bases are multiples of 16
  int offA[4], offB[4];
#pragma unroll
  for (int i = 0; i < 4; ++i) {
    const int ra = wr * 64 + i * 16 + m16;
    const int rb = wc * 64 + i * 16 + m16;
    offA[i] = ra * 32 + sw * 8;
    offB[i] = rb * 32 + sw * 8;
  }

  f32x4 acc[4][4];
#pragma unroll
  for (int i = 0; i < 4; ++i)
#pragma unroll
    for (int j = 0; j < 4; ++j) { acc[i][j][0] = 0.f; acc[i][j][1] = 0.f; acc[i][j][2] = 0.f; acc[i][j][3] = 0.f; }

  // prologue: stage k0=0 into buf 0
  async_cp16(gA0, &As[0][oS0]);
  async_cp16(gA1, &As[0][oS1]);
  async_cp16(gB0, &Bs[0][oS0]);
  async_cp16(gB1, &Bs[0][oS1]);
  __syncthreads();

  int cur = 0;
  for (int k0 = 0; k0 < K; k0 += 32) {
    const int nk = k0 + 32;
    if (nk < K) {                      // prefetch next K-step into the other buffer
      unsigned short* an = &As[cur ^ 1][0];
      unsigned short* bn2 = &Bs[cur ^ 1][0];
      async_cp16(gA0 + nk, an + oS0);
      async_cp16(gA1 + nk, an + oS1);
      async_cp16(gB0 + nk, bn2 + oS0);
      async_cp16(gB1 + nk, bn2 + oS1);
    }
    const unsigned short* Ac = &As[cur][0];
    const unsigned short* Bc = &Bs[cur][0];
    short8 af[4], bfr[4];
#pragma unroll
    for (int i = 0; i < 4; ++i) {
      af[i]  = *(const short8*)(Ac + offA[i]);
      bfr[i] = *(const short8*)(Bc + offB[i]);
    }
#pragma unroll
    for (int i = 0; i < 4; ++i)
#pragma unroll
      for (int j = 0; j < 4; ++j)
        acc[i][j] = __builtin_amdgcn_mfma_f32_16x16x32_bf16(af[i], bfr[j], acc[i][j], 0, 0, 0);
    __syncthreads();   // drains prefetch (latency already hidden by MFMA) + read fence
    cur ^= 1;
  }

  if (mode == 0) {
#pragma unroll
    for (int j = 0; j < 4; ++j) {
      const int n = bn + wc * 64 + j * 16 + m16;
      const float bj = bias[n];
#pragma unroll
      for (int i = 0; i < 4; ++i) {
        const int mrow = bm + wr * 64 + i * 16 + quad * 4;
#pragma unroll
        for (int r2 = 0; r2 < 4; ++r2)
          C[(size_t)(mrow + r2) * N + n] = acc[i][j][r2] + bj;
      }
    }
  } else {
    // QKV epilogue: segment decode (wave-uniform: col base is 64-aligned, 768 % 64 == 0)
    const int segbase = bn + wc * 64;
    const int which = segbase / D_;
    const int h = (segbase - which * D_) >> 6;
    unsigned short* dstT = (which == 0) ? qp : (which == 1) ? kp : vp;
    float bj[4];
#pragma unroll
    for (int og = 0; og < 4; ++og) bj[og] = bias[segbase + og * 16 + m16];
    // RoPE inv freqs: d = og*16+m16, idx = d&31 -> m16 (og even) or 16+m16 (og odd)
    const float invfA = exp2f(-(float)m16 * kLog2_10000_div32);
    const float invfB = exp2f(-(float)(16 + m16) * kLog2_10000_div32);

#pragma unroll
    for (int i = 0; i < 4; ++i) {
      const int mrow = bm + wr * 64 + i * 16 + quad * 4;
#pragma unroll
      for (int r2 = 0; r2 < 4; ++r2) {
        const int m = mrow + r2;
        const int bi = m >> 11;
        const int li = m & (L_ - 1);
        float vals[4];
#pragma unroll
        for (int og = 0; og < 4; ++og) vals[og] = acc[i][og][r2] + bj[og];
        unsigned short* drow = dstT + (((size_t)(bi * H_ + h)) * L_ + li) * HD_;
        if (which == 2) {
#pragma unroll
          for (int og = 0; og < 4; ++og) drow[og * 16 + m16] = f2bf(vals[og]);
        } else {
          const float fl = (float)li;
#pragma unroll
          for (int og = 0; og < 4; ++og) {
            const int d = og * 16 + m16;
            const float theta = fl * ((og & 1) ? invfB : invfA);
            float sv, cv;
            __sincosf(theta, &sv, &cv);
            const float part = vals[og ^ 2];          // pre-rope partner at d^32
            const float rot = (og < 2) ? -part : part;  // rotate_half sign
            drow[d] = f2bf(vals[og] * cv + rot * sv);
          }
        }
      }
    }
  }
}

// ============================ Fused causal attention (MFMA bf16) ============================
// v3: pass 1 = barrier-free K streaming from global (registers only, no LDS).
// pass 2 = K fragments from global; V^T tile staged ONCE per block via global_load_lds
// into a chunk-XOR-swizzled double buffer (ONE barrier per k-tile; prefetch issued before
// compute so the drain at the barrier is cheap). Probs stores are PLAIN cached stores
// (v2's nontemporal scalar stores caused ~1.9x HBM write amplification).
// LDS = 16KB (V dbuf) + 9KB (Pb) = 25.6KB -> 6 blocks/CU.
__global__ __launch_bounds__(256) void attn_mfma_kernel(
    const unsigned short* __restrict__ qb, const unsigned short* __restrict__ kb,
    const unsigned short* __restrict__ vt, float* __restrict__ probs,
    unsigned short* __restrict__ attnb)
{
  __shared__ __align__(16) unsigned short Vs[2][64 * 64];  // [buf][row*64 + pos*8], pos = chunk^(row&7)
  __shared__ __align__(16) unsigned short Pb[4][16][72];   // per-wave P tile

  const int tid  = threadIdx.x;
  const int w    = tid >> 6;
  const int lane = tid & 63;
  const int m16  = lane & 15;
  const int quad = lane >> 4;

  const int bh = blockIdx.y;
  const int qt = (int)gridDim.x - 1 - (int)blockIdx.x;   // big tiles first
  const int q0 = qt * 64;
  const int bb = bh / H_;
  const int hh = bh - bb * H_;
  const int ktiles = qt + 1;
  const int qrow_base = q0 + w * 16;

  const unsigned short* kbase = kb + (size_t)bh * L_ * HD_;
  const unsigned short* vbase = vt + (size_t)bh * HD_ * L_;

  // Q fragments (registers, reused across all k-tiles)
  const unsigned short* qp = qb + ((size_t)bh * L_ + qrow_base + m16) * HD_ + quad * 8;
  const short8 qf0 = *(const short8*)(qp);
  const short8 qf1 = *(const short8*)(qp + 32);

  // K fragment base: row cg*16+m16 of tile k0, col chunk quad (b0) / quad+4 (b1)
  const unsigned short* kfp = kbase + (size_t)m16 * HD_ + quad * 8;

  // ---------------- pass 1: row sums (pure streaming, no LDS, no barriers) ----------------
  float lsum[4] = {0.f, 0.f, 0.f, 0.f};
  for (int kt = 0; kt < ktiles; ++kt) {
    const int k0 = kt * 64;
    short8 kb0[4], kb1[4];
#pragma unroll
    for (int cg = 0; cg < 4; ++cg) {
      const unsigned short* kr = kfp + (size_t)(k0 + cg * 16) * HD_;
      kb0[cg] = *(const short8*)(kr);
      kb1[cg] = *(const short8*)(kr + 32);
    }
#pragma unroll
    for (int cg = 0; cg < 4; ++cg) {
      f32x4 s = {0.f, 0.f, 0.f, 0.f};
      s = __builtin_amdgcn_mfma_f32_16x16x32_bf16(qf0, kb0[cg], s, 0, 0, 0);
      s = __builtin_amdgcn_mfma_f32_16x16x32_bf16(qf1, kb1[cg], s, 0, 0, 0);
      const int kcol = k0 + cg * 16 + m16;
#pragma unroll
      for (int r2 = 0; r2 < 4; ++r2) {
        const int qrow = qrow_base + quad * 4 + r2;
        const float e = __expf(s[r2] * kScale);
        lsum[r2] += (kcol <= qrow) ? e : 0.f;
      }
    }
  }
  float linv[4];
#pragma unroll
  for (int r2 = 0; r2 < 4; ++r2) {
    float v = lsum[r2];
    v += __shfl_xor(v, 1, 64);
    v += __shfl_xor(v, 2, 64);
    v += __shfl_xor(v, 4, 64);
    v += __shfl_xor(v, 8, 64);
    linv[r2] = 1.f / v;
  }

  // ---------------- pass 2: probs + PV (dbuf async V staging, one barrier/tile) ----------
  f32x4 oacc[4];
#pragma unroll
  for (int og = 0; og < 4; ++og) { oacc[og][0]=0.f; oacc[og][1]=0.f; oacc[og][2]=0.f; oacc[og][3]=0.f; }

  // V staging geometry: 512 slots of 16B; slot s -> row r=s>>3, LDS pos s&7 holds data
  // chunk (s&7)^(r&7). Wave w: call0 slots w*64+lane, call1 slots 256+w*64+lane
  // (LDS dest = wave-uniform base + lane*16, as global_load_lds requires).
  const int vs0 = w * 64 + lane;
  const int vs1 = vs0 + 256;
  const int vr0 = vs0 >> 3, vc0 = ((vs0 & 7) ^ (vr0 & 7)) * 8;
  const int vr1 = vs1 >> 3, vc1 = ((vs1 & 7) ^ (vr1 & 7)) * 8;
  const unsigned short* gV0 = vbase + (size_t)vr0 * L_ + vc0;
  const unsigned short* gV1 = vbase + (size_t)vr1 * L_ + vc1;
  const int oV0 = (w * 64) * 8;          // wave-uniform LDS short-offsets
  const int oV1 = 2048 + (w * 64) * 8;
  const int swv = m16 & 7;               // read-side swizzle key (row = og*16+m16)

  // prologue: stage V tile 0 into buf 0
  async_cp16(gV0, &Vs[0][oV0]);
  async_cp16(gV1, &Vs[0][oV1]);
  __syncthreads();

  int cur = 0;
  for (int kt = 0; kt < ktiles; ++kt) {
    const int k0 = kt * 64;
    if (kt + 1 < ktiles) {               // prefetch next V tile into other buffer
      unsigned short* nb = &Vs[cur ^ 1][0];
      async_cp16(gV0 + k0 + 64, nb + oV0);
      async_cp16(gV1 + k0 + 64, nb + oV1);
    }
    // K fragments from global (L2-resident)
    short8 kb0[4], kb1[4];
#pragma unroll
    for (int cg = 0; cg < 4; ++cg) {
      const unsigned short* kr = kfp + (size_t)(k0 + cg * 16) * HD_;
      kb0[cg] = *(const short8*)(kr);
      kb1[cg] = *(const short8*)(kr + 32);
    }
    // QK^T + normalize + probs store (plain, cached) + P tile
#pragma unroll
    for (int cg = 0; cg < 4; ++cg) {
      f32x4 s = {0.f, 0.f, 0.f, 0.f};
      s = __builtin_amdgcn_mfma_f32_16x16x32_bf16(qf0, kb0[cg], s, 0, 0, 0);
      s = __builtin_amdgcn_mfma_f32_16x16x32_bf16(qf1, kb1[cg], s, 0, 0, 0);
      const int kcol = k0 + cg * 16 + m16;
#pragma unroll
      for (int r2 = 0; r2 < 4; ++r2) {
        const int qrow = qrow_base + quad * 4 + r2;
        const float p = (kcol <= qrow) ? __expf(s[r2] * kScale) * linv[r2] : 0.f;
        probs[((size_t)bh * L_ + qrow) * L_ + kcol] = p;
        Pb[w][quad * 4 + r2][cg * 16 + m16] = f2bf(p);
      }
    }
    // PV: A = P tile (per-wave LDS transpose), B = V^T fragments from swizzled dbuf
    const short8 pa0 = *(const short8*)&Pb[w][m16][quad * 8];
    const short8 pa1 = *(const short8*)&Pb[w][m16][32 + quad * 8];
    const unsigned short* Vb = &Vs[cur][0];
#pragma unroll
    for (int og = 0; og < 4; ++og) {
      const int r = og * 16 + m16;
      const short8 v0 = *(const short8*)(Vb + r * 64 + ((quad ^ swv) * 8));
      const short8 v1 = *(const short8*)(Vb + r * 64 + (((quad + 4) ^ swv) * 8));
      oacc[og] = __builtin_amdgcn_mfma_f32_16x16x32_bf16(pa0, v0, oacc[og], 0, 0, 0);
      oacc[og] = __builtin_amdgcn_mfma_f32_16x16x32_bf16(pa1, v1, oacc[og], 0, 0, 0);
    }
    __syncthreads();   // publishes prefetched tile; fences reads of cur before overwrite
    cur ^= 1;
  }

  // O epilogue -> attn [B,L,D] bf16 (feeds out-proj GEMM directly)
#pragma unroll
  for (int og = 0; og < 4; ++og)
#pragma unroll
    for (int r2 = 0; r2 < 4; ++r2)
      attnb[((size_t)bb * L_ + qrow_base + quad * 4 + r2) * D_ + hh * HD_ + og * 16 + m16] =
          f2bf(oacc[og][r2]);

  // zero-fill masked probs columns beyond processed tiles (plain cached stores)
  {
    const f32x4 z4 = {0.f, 0.f, 0.f, 0.f};
#pragma unroll
    for (int r2 = 0; r2 < 4; ++r2) {
      float* pr = probs + ((size_t)bh * L_ + qrow_base + quad * 4 + r2) * L_;
      for (int c0z = ktiles * 64; c0z < L_; c0z += 64)
        *(f32x4*)(pr + c0z + m16 * 4) = z4;
    }
  }
}

// ============================ launcher ============================
extern "C" void kernel_launch(void* const* d_in, const int* in_sizes, int n_in,
                              void* d_out, int out_size, void* d_ws, size_t ws_size,
                              hipStream_t stream)
{
  const float* x     = (const float*)d_in[0];
  const float* w_qkv = (const float*)d_in[1];
  const float* b_qkv = (const float*)d_in[2];
  const float* w_out = (const float*)d_in[3];
  const float* b_out = (const float*)d_in[4];

  float* out   = (float*)d_out;
  float* probs = out + OUT_ELEMS;

  const size_t NE = (size_t)B_ * H_ * L_ * HD_;   // 3145728
  unsigned short* qbw   = (unsigned short*)d_ws;  // bf16 q [B,H,L,64]
  unsigned short* kbw   = qbw + NE;
  unsigned short* vbw   = kbw + NE;
  unsigned short* vtw   = vbw + NE;               // v^T [B,H,64,L]
  unsigned short* xbw   = vtw + NE;               // bf16 x [M,K]
  unsigned short* attnb = xbw + NE;               // bf16 attn [B,L,D]
  unsigned short* wqT   = attnb + NE;             // bf16 w_qkv^T [2304,768]
  unsigned short* woT   = wqT + (size_t)N3_ * D_; // bf16 w_out^T [768,768]
  // total: 6*6.29MB + 3.54MB + 1.18MB = 42.5 MB

  // 1) conversions (independent)
  bf16conv_kernel<<<(int)(OUT_ELEMS / 8 / 256), 256, 0, stream>>>(x, xbw);
  wtrans_kernel<<<dim3(N3_ / 64, D_ / 64), 256, 0, stream>>>(w_qkv, wqT, D_, N3_);
  wtrans_kernel<<<dim3(D_ / 64, D_ / 64), 256, 0, stream>>>(w_out, woT, D_, D_);

  // 2) QKV projection (MFMA) + bias + fused RoPE + head-split -> bf16 q/k/v
  gemm_mfma_kernel<<<dim3(N3_ / 128, M_ / 128), 256, 0, stream>>>(
      xbw, wqT, b_qkv, nullptr, M_, N3_, D_, 1, qbw, kbw, vbw);

  // 3) V transpose for PV B-operand
  vtrans_kernel<<<dim3(L_ / 64, B_ * H_), 256, 0, stream>>>(vbw, vtw);

  // 4) fused causal attention: probs + attn (bf16)
  attn_mfma_kernel<<<dim3(L_ / 64, B_ * H_), 256, 0, stream>>>(qbw, kbw, vtw, probs, attnb);

  // 5) output projection (MFMA) + bias -> fp32 out
  gemm_mfma_kernel<<<dim3(D_ / 128, M_ / 128), 256, 0, stream>>>(
      attnb, woT, b_out, out, M_, D_, D_, 0, nullptr, nullptr, nullptr);
}

// Round 5
// 542.123 us; speedup vs baseline: 1.4541x; 1.1452x over previous
//
#include <hip/hip_runtime.h>
#include <math.h>

// Problem constants (MultiHeadAttention: B=2, L=2048, D=768, H=12, HD=64)
#define B_  2
#define L_  2048
#define D_  768
#define H_  12
#define HD_ 64
#define M_  (B_*L_)          // 4096 rows for the GEMMs
#define N3_ (3*D_)           // 2304
#define OUT_ELEMS ((size_t)B_*L_*D_)   // 3145728

static constexpr float kScale = 0.022097086912079608f;  // 1/sqrt(2048) (ref divides by sqrt(L))
static constexpr float kLog2_10000_div32 = 0.415241011860920f;

typedef __attribute__((ext_vector_type(8))) short short8;
typedef __attribute__((ext_vector_type(4))) float f32x4;

__device__ __forceinline__ unsigned short f2bf(float f) {
  union { float f; unsigned u; } v; v.f = f;
  unsigned r = v.u + 0x7FFFu + ((v.u >> 16) & 1u);   // round-to-nearest-even
  return (unsigned short)(r >> 16);
}

__device__ __forceinline__ void async_cp16(const void* g, void* l) {
  __builtin_amdgcn_global_load_lds((const __attribute__((address_space(1))) void*)g,
                                   (__attribute__((address_space(3))) void*)l, 16, 0, 0);
}

// ===================== convert fp32 -> bf16 (straight) =====================
__global__ __launch_bounds__(256) void bf16conv_kernel(const float* __restrict__ in,
                                                       unsigned short* __restrict__ out)
{
  const int idx = blockIdx.x * 256 + threadIdx.x;
  const float* src = in + (size_t)idx * 8;
  float4 a = *(const float4*)src;
  float4 b = *(const float4*)(src + 4);
  unsigned short t[8];
  t[0] = f2bf(a.x); t[1] = f2bf(a.y); t[2] = f2bf(a.z); t[3] = f2bf(a.w);
  t[4] = f2bf(b.x); t[5] = f2bf(b.y); t[6] = f2bf(b.z); t[7] = f2bf(b.w);
  *(uint4*)(out + (size_t)idx * 8) = *(uint4*)t;
}

// ===================== weight transpose+convert: fp32 [K][N] -> bf16 [N][K] =====================
__global__ __launch_bounds__(256) void wtrans_kernel(const float* __restrict__ in,
                                                     unsigned short* __restrict__ out,
                                                     int K, int N)
{
  __shared__ __align__(16) unsigned short T[64][72];
  const int n0 = blockIdx.x * 64;
  const int k0 = blockIdx.y * 64;
  const int tid = threadIdx.x;
  const int row = tid >> 2;          // 0..63
  const int col = (tid & 3) * 16;    // 0,16,32,48
  {
    const float* src = in + (size_t)(k0 + row) * N + n0 + col;
    unsigned short tmp[16];
#pragma unroll
    for (int j = 0; j < 16; j += 4) {
      float4 v = *(const float4*)(src + j);
      tmp[j] = f2bf(v.x); tmp[j + 1] = f2bf(v.y); tmp[j + 2] = f2bf(v.z); tmp[j + 3] = f2bf(v.w);
    }
    *(uint4*)&T[row][col]     = *(uint4*)tmp;       // T[k][n]
    *(uint4*)&T[row][col + 8] = *(uint4*)(tmp + 8);
  }
  __syncthreads();
  unsigned short tmp[16];
#pragma unroll
  for (int j = 0; j < 16; ++j) tmp[j] = T[col + j][row];   // gather k-run for fixed n=row
  unsigned short* dst = out + (size_t)(n0 + row) * K + k0 + col;
  *(uint4*)dst       = *(uint4*)tmp;
  *(uint4*)(dst + 8) = *(uint4*)(tmp + 8);
}

// ===================== V transpose bf16: [B,H,L,64] -> [B,H,64,L] =====================
__global__ __launch_bounds__(256) void vtrans_kernel(const unsigned short* __restrict__ vb,
                                                     unsigned short* __restrict__ vt)
{
  __shared__ __align__(16) unsigned short T[64][72];
  const int bh = blockIdx.y;
  const int l0 = blockIdx.x * 64;
  const int tid = threadIdx.x;
  const int row = tid >> 2;
  const int col = (tid & 3) * 16;
  {
    const unsigned short* src = vb + ((size_t)bh * L_ + l0 + row) * HD_ + col;
    *(uint4*)&T[row][col]     = *(const uint4*)src;        // T[l][d]
    *(uint4*)&T[row][col + 8] = *(const uint4*)(src + 8);
  }
  __syncthreads();
  unsigned short tmp[16];
#pragma unroll
  for (int j = 0; j < 16; ++j) tmp[j] = T[col + j][row];   // l-run for fixed d=row
  unsigned short* dst = vt + ((size_t)bh * HD_ + row) * L_ + l0 + col;
  *(uint4*)dst       = *(uint4*)tmp;
  *(uint4*)(dst + 8) = *(uint4*)(tmp + 8);
}

// ===================== bf16 MFMA GEMM: C[M][N] = A[M][K] * Bt[N][K]^T + bias =====================
// 128x128 tile, BK=32, 4 waves each computing a 64x64 quadrant (4x4 of 16x16x32 mfma).
// DOUBLE-BUFFERED async staging: stage k0+32 into buf^1 BEFORE computing buf, ONE
// __syncthreads per K-step. Staging via global_load_lds(16B) with chunk^=(row&3) XOR swizzle.
// mode 0: fp32 C store.  mode 1: QKV -> bf16 q/k/v head-split with FUSED RoPE on q,k.
__global__ __launch_bounds__(256) void gemm_mfma_kernel(
    const unsigned short* __restrict__ A, const unsigned short* __restrict__ Bt,
    const float* __restrict__ bias, float* __restrict__ C,
    int M, int N, int K, int mode,
    unsigned short* __restrict__ qp, unsigned short* __restrict__ kp,
    unsigned short* __restrict__ vp)
{
  __shared__ __align__(16) unsigned short As[2][128 * 32];
  __shared__ __align__(16) unsigned short Bs[2][128 * 32];

  const int tid  = threadIdx.x;
  const int w    = tid >> 6;
  const int lane = tid & 63;
  const int m16  = lane & 15;
  const int quad = lane >> 4;
  const int wr   = w & 1;        // row half of quadrant
  const int wc   = w >> 1;       // col half

  const int bm = blockIdx.y * 128;
  const int bn = blockIdx.x * 128;

  // staging: wave w covers slots [w*128, w*128+128); slot s -> row s/4, stored chunk s%4,
  // fetched data chunk (s%4)^(row&3)
  const int s0 = w * 128 + lane;
  const int s1 = s0 + 64;
  const int r0 = s0 >> 2, c0 = (s0 & 3) ^ (r0 & 3);
  const int r1 = s1 >> 2, c1 = (s1 & 3) ^ (r1 & 3);
  const unsigned short* gA0 = A + (size_t)(bm + r0) * K + c0 * 8;
  const unsigned short* gA1 = A + (size_t)(bm + r1) * K + c1 * 8;
  const unsigned short* gB0 = Bt + (size_t)(bn + r0) * K + c0 * 8;
  const unsigned short* gB1 = Bt + (size_t)(bn + r1) * K + c1 * 8;
  const int oS0 = (w * 128) * 8;        // LDS short-offset for call 0 (wave-uniform)
  const int oS1 = (w * 128 + 64) * 8;   // call 1

  // fragment LDS offsets (k0-invariant): row r, chunk quad^(r&3)
  const int sw = quad ^ (m16 & 3);   // (r&3)==(m16&3) since tile bases are multiples of 16
  int offA[4], offB[4];
#pragma unroll
  for (int i = 0; i < 4; ++i) {
    const int ra = wr * 64 + i * 16 + m16;
    const int rb = wc * 64 + i * 16 + m16;
    offA[i] = ra * 32 + sw * 8;
    offB[i] = rb * 32 + sw * 8;
  }

  f32x4 acc[4][4];
#pragma unroll
  for (int i = 0; i < 4; ++i)
#pragma unroll
    for (int j = 0; j < 4; ++j) { acc[i][j][0] = 0.f; acc[i][j][1] = 0.f; acc[i][j][2] = 0.f; acc[i][j][3] = 0.f; }

  // prologue: stage k0=0 into buf 0
  async_cp16(gA0, &As[0][oS0]);
  async_cp16(gA1, &As[0][oS1]);
  async_cp16(gB0, &Bs[0][oS0]);
  async_cp16(gB1, &Bs[0][oS1]);
  __syncthreads();

  int cur = 0;
  for (int k0 = 0; k0 < K; k0 += 32) {
    const int nk = k0 + 32;
    if (nk < K) {                      // prefetch next K-step into the other buffer
      unsigned short* an = &As[cur ^ 1][0];
      unsigned short* bn2 = &Bs[cur ^ 1][0];
      async_cp16(gA0 + nk, an + oS0);
      async_cp16(gA1 + nk, an + oS1);
      async_cp16(gB0 + nk, bn2 + oS0);
      async_cp16(gB1 + nk, bn2 + oS1);
    }
    const unsigned short* Ac = &As[cur][0];
    const unsigned short* Bc = &Bs[cur][0];
    short8 af[4], bfr[4];
#pragma unroll
    for (int i = 0; i < 4; ++i) {
      af[i]  = *(const short8*)(Ac + offA[i]);
      bfr[i] = *(const short8*)(Bc + offB[i]);
    }
#pragma unroll
    for (int i = 0; i < 4; ++i)
#pragma unroll
      for (int j = 0; j < 4; ++j)
        acc[i][j] = __builtin_amdgcn_mfma_f32_16x16x32_bf16(af[i], bfr[j], acc[i][j], 0, 0, 0);
    __syncthreads();   // drains prefetch (latency already hidden by MFMA) + read fence
    cur ^= 1;
  }

  if (mode == 0) {
#pragma unroll
    for (int j = 0; j < 4; ++j) {
      const int n = bn + wc * 64 + j * 16 + m16;
      const float bj = bias[n];
#pragma unroll
      for (int i = 0; i < 4; ++i) {
        const int mrow = bm + wr * 64 + i * 16 + quad * 4;
#pragma unroll
        for (int r2 = 0; r2 < 4; ++r2)
          C[(size_t)(mrow + r2) * N + n] = acc[i][j][r2] + bj;
      }
    }
  } else {
    // QKV epilogue: segment decode (wave-uniform: col base is 64-aligned, 768 % 64 == 0)
    const int segbase = bn + wc * 64;
    const int which = segbase / D_;
    const int h = (segbase - which * D_) >> 6;
    unsigned short* dstT = (which == 0) ? qp : (which == 1) ? kp : vp;
    float bj[4];
#pragma unroll
    for (int og = 0; og < 4; ++og) bj[og] = bias[segbase + og * 16 + m16];
    // RoPE inv freqs: d = og*16+m16, idx = d&31 -> m16 (og even) or 16+m16 (og odd)
    const float invfA = exp2f(-(float)m16 * kLog2_10000_div32);
    const float invfB = exp2f(-(float)(16 + m16) * kLog2_10000_div32);

#pragma unroll
    for (int i = 0; i < 4; ++i) {
      const int mrow = bm + wr * 64 + i * 16 + quad * 4;
#pragma unroll
      for (int r2 = 0; r2 < 4; ++r2) {
        const int m = mrow + r2;
        const int bi = m >> 11;
        const int li = m & (L_ - 1);
        float vals[4];
#pragma unroll
        for (int og = 0; og < 4; ++og) vals[og] = acc[i][og][r2] + bj[og];
        unsigned short* drow = dstT + (((size_t)(bi * H_ + h)) * L_ + li) * HD_;
        if (which == 2) {
#pragma unroll
          for (int og = 0; og < 4; ++og) drow[og * 16 + m16] = f2bf(vals[og]);
        } else {
          const float fl = (float)li;
#pragma unroll
          for (int og = 0; og < 4; ++og) {
            const int d = og * 16 + m16;
            const float theta = fl * ((og & 1) ? invfB : invfA);
            float sv, cv;
            __sincosf(theta, &sv, &cv);
            const float part = vals[og ^ 2];          // pre-rope partner at d^32
            const float rot = (og < 2) ? -part : part;  // rotate_half sign
            drow[d] = f2bf(vals[og] * cv + rot * sv);
          }
        }
      }
    }
  }
}

// ============================ Fused causal attention (MFMA bf16) ============================
// v4: COOPERATIVE async staging (the baseline's amortization) + v3's 1-barrier dbuf pipeline.
// Both passes stage the K tile (pass 2 also V^T) once per block via global_load_lds into
// XOR-swizzled double buffers; tile t+1's loads are issued at the top of iteration t so
// their latency hides under QK^T/exp/PV; ONE __syncthreads per tile publishes the prefetch
// and fences buffer reuse. Plain cached probs stores. setprio(1) around the PV MFMA cluster.
// LDS = 16KB (K dbuf) + 16KB (V dbuf) + 9.2KB (Pb) = 41.2KB -> 3 blocks/CU (= grid limit).
__global__ __launch_bounds__(256) void attn_mfma_kernel(
    const unsigned short* __restrict__ qb, const unsigned short* __restrict__ kb,
    const unsigned short* __restrict__ vt, float* __restrict__ probs,
    unsigned short* __restrict__ attnb)
{
  __shared__ __align__(16) unsigned short Ks[2][64 * 64];  // [buf][row*64 + pos*8]
  __shared__ __align__(16) unsigned short Vs[2][64 * 64];  // [buf][d*64 + pos*8]
  __shared__ __align__(16) unsigned short Pb[4][16][72];   // per-wave P tile

  const int tid  = threadIdx.x;
  const int w    = tid >> 6;
  const int lane = tid & 63;
  const int m16  = lane & 15;
  const int quad = lane >> 4;

  const int bh = blockIdx.y;
  const int qt = (int)gridDim.x - 1 - (int)blockIdx.x;   // big tiles first
  const int q0 = qt * 64;
  const int bb = bh / H_;
  const int hh = bh - bb * H_;
  const int ktiles = qt + 1;
  const int qrow_base = q0 + w * 16;

  const unsigned short* kbase = kb + (size_t)bh * L_ * HD_;
  const unsigned short* vbase = vt + (size_t)bh * HD_ * L_;

  // Q fragments (registers, reused across all k-tiles)
  const unsigned short* qp = qb + ((size_t)bh * L_ + qrow_base + m16) * HD_ + quad * 8;
  const short8 qf0 = *(const short8*)(qp);
  const short8 qf1 = *(const short8*)(qp + 32);

  // cooperative 64x64-short (8KB) tile staging, shared geometry for K and V^T:
  // 512 slots of 16B; slot s -> row s>>3, LDS pos s&7 holds global chunk (s&7)^(row&7).
  // Thread handles slots tid (call 0) and tid+256 (call 1); LDS dest is wave-uniform
  // base + lane*16 as global_load_lds requires.
  const int s0g = tid, s1g = tid + 256;
  const int r0 = s0g >> 3, c0 = (s0g & 7) ^ (r0 & 7);
  const int r1 = s1g >> 3, c1 = (s1g & 7) ^ (r1 & 7);
  const unsigned short* gK0 = kbase + (size_t)r0 * HD_ + c0 * 8;   // advance: +kt*64*HD_
  const unsigned short* gK1 = kbase + (size_t)r1 * HD_ + c1 * 8;
  const unsigned short* gV0 = vbase + (size_t)r0 * L_ + c0 * 8;    // advance: +kt*64
  const unsigned short* gV1 = vbase + (size_t)r1 * L_ + c1 * 8;
  const int oL0 = (w * 64) * 8;          // wave-uniform LDS short-offset, call 0
  const int oL1 = (256 + w * 64) * 8;    // call 1
  const int swk = m16 & 7;               // read-side swizzle key: fragment row % 8 == m16 % 8

  // ---------------- pass 1: row sums (async dbuf K staging, 1 barrier/tile) ----------------
  float lsum[4] = {0.f, 0.f, 0.f, 0.f};
  {
    async_cp16(gK0, &Ks[0][oL0]);
    async_cp16(gK1, &Ks[0][oL1]);
    __syncthreads();
    int cur = 0;
    for (int kt = 0; kt < ktiles; ++kt) {
      const int k0 = kt * 64;
      if (kt + 1 < ktiles) {
        const size_t adv = (size_t)(kt + 1) * 64 * HD_;
        async_cp16(gK0 + adv, &Ks[cur ^ 1][oL0]);
        async_cp16(gK1 + adv, &Ks[cur ^ 1][oL1]);
      }
      const unsigned short* Kc = &Ks[cur][0];
#pragma unroll
      for (int cg = 0; cg < 4; ++cg) {
        const int r = cg * 16 + m16;
        const short8 b0 = *(const short8*)(Kc + r * 64 + ((quad ^ swk) * 8));
        const short8 b1 = *(const short8*)(Kc + r * 64 + (((quad + 4) ^ swk) * 8));
        f32x4 s = {0.f, 0.f, 0.f, 0.f};
        s = __builtin_amdgcn_mfma_f32_16x16x32_bf16(qf0, b0, s, 0, 0, 0);
        s = __builtin_amdgcn_mfma_f32_16x16x32_bf16(qf1, b1, s, 0, 0, 0);
        const int kcol = k0 + cg * 16 + m16;
#pragma unroll
        for (int r2 = 0; r2 < 4; ++r2) {
          const int qrow = qrow_base + quad * 4 + r2;
          const float e = __expf(s[r2] * kScale);
          lsum[r2] += (kcol <= qrow) ? e : 0.f;
        }
      }
      __syncthreads();   // publishes prefetched tile; fences reads before buffer reuse
      cur ^= 1;
    }
  }
  float linv[4];
#pragma unroll
  for (int r2 = 0; r2 < 4; ++r2) {
    float v = lsum[r2];
    v += __shfl_xor(v, 1, 64);
    v += __shfl_xor(v, 2, 64);
    v += __shfl_xor(v, 4, 64);
    v += __shfl_xor(v, 8, 64);
    linv[r2] = 1.f / v;
  }

  // ---------------- pass 2: probs + PV (async dbuf K+V staging, 1 barrier/tile) ----------
  f32x4 oacc[4];
#pragma unroll
  for (int og = 0; og < 4; ++og) { oacc[og][0]=0.f; oacc[og][1]=0.f; oacc[og][2]=0.f; oacc[og][3]=0.f; }

  {
    // restage tile 0 (all pass-1 reads completed at its final barrier)
    async_cp16(gK0, &Ks[0][oL0]);
    async_cp16(gK1, &Ks[0][oL1]);
    async_cp16(gV0, &Vs[0][oL0]);
    async_cp16(gV1, &Vs[0][oL1]);
    __syncthreads();
    int cur = 0;
    for (int kt = 0; kt < ktiles; ++kt) {
      const int k0 = kt * 64;
      if (kt + 1 < ktiles) {
        const size_t advK = (size_t)(kt + 1) * 64 * HD_;
        const int advV = (kt + 1) * 64;
        async_cp16(gK0 + advK, &Ks[cur ^ 1][oL0]);
        async_cp16(gK1 + advK, &Ks[cur ^ 1][oL1]);
        async_cp16(gV0 + advV, &Vs[cur ^ 1][oL0]);
        async_cp16(gV1 + advV, &Vs[cur ^ 1][oL1]);
      }
      const unsigned short* Kc = &Ks[cur][0];
      const unsigned short* Vc = &Vs[cur][0];
      // QK^T + normalize + probs store (plain, cached) + P tile
#pragma unroll
      for (int cg = 0; cg < 4; ++cg) {
        const int r = cg * 16 + m16;
        const short8 b0 = *(const short8*)(Kc + r * 64 + ((quad ^ swk) * 8));
        const short8 b1 = *(const short8*)(Kc + r * 64 + (((quad + 4) ^ swk) * 8));
        f32x4 s = {0.f, 0.f, 0.f, 0.f};
        s = __builtin_amdgcn_mfma_f32_16x16x32_bf16(qf0, b0, s, 0, 0, 0);
        s = __builtin_amdgcn_mfma_f32_16x16x32_bf16(qf1, b1, s, 0, 0, 0);
        const int kcol = k0 + cg * 16 + m16;
#pragma unroll
        for (int r2 = 0; r2 < 4; ++r2) {
          const int qrow = qrow_base + quad * 4 + r2;
          const float p = (kcol <= qrow) ? __expf(s[r2] * kScale) * linv[r2] : 0.f;
          probs[((size_t)bh * L_ + qrow) * L_ + kcol] = p;
          Pb[w][quad * 4 + r2][cg * 16 + m16] = f2bf(p);
        }
      }
      // PV: A = P tile (per-wave LDS transpose), B = V^T fragments from swizzled dbuf
      const short8 pa0 = *(const short8*)&Pb[w][m16][quad * 8];
      const short8 pa1 = *(const short8*)&Pb[w][m16][32 + quad * 8];
      __builtin_amdgcn_s_setprio(1);
#pragma unroll
      for (int og = 0; og < 4; ++og) {
        const int r = og * 16 + m16;
        const short8 v0 = *(const short8*)(Vc + r * 64 + ((quad ^ swk) * 8));
        const short8 v1 = *(const short8*)(Vc + r * 64 + (((quad + 4) ^ swk) * 8));
        oacc[og] = __builtin_amdgcn_mfma_f32_16x16x32_bf16(pa0, v0, oacc[og], 0, 0, 0);
        oacc[og] = __builtin_amdgcn_mfma_f32_16x16x32_bf16(pa1, v1, oacc[og], 0, 0, 0);
      }
      __builtin_amdgcn_s_setprio(0);
      __syncthreads();   // publishes prefetched tiles; fences reads before buffer reuse
      cur ^= 1;
    }
  }

  // O epilogue -> attn [B,L,D] bf16 (feeds out-proj GEMM directly)
#pragma unroll
  for (int og = 0; og < 4; ++og)
#pragma unroll
    for (int r2 = 0; r2 < 4; ++r2)
      attnb[((size_t)bb * L_ + qrow_base + quad * 4 + r2) * D_ + hh * HD_ + og * 16 + m16] =
          f2bf(oacc[og][r2]);

  // zero-fill masked probs columns beyond processed tiles (plain cached stores)
  {
    const f32x4 z4 = {0.f, 0.f, 0.f, 0.f};
#pragma unroll
    for (int r2 = 0; r2 < 4; ++r2) {
      float* pr = probs + ((size_t)bh * L_ + qrow_base + quad * 4 + r2) * L_;
      for (int c0z = ktiles * 64; c0z < L_; c0z += 64)
        *(f32x4*)(pr + c0z + m16 * 4) = z4;
    }
  }
}

// ============================ launcher ============================
extern "C" void kernel_launch(void* const* d_in, const int* in_sizes, int n_in,
                              void* d_out, int out_size, void* d_ws, size_t ws_size,
                              hipStream_t stream)
{
  const float* x     = (const float*)d_in[0];
  const float* w_qkv = (const float*)d_in[1];
  const float* b_qkv = (const float*)d_in[2];
  const float* w_out = (const float*)d_in[3];
  const float* b_out = (const float*)d_in[4];

  float* out   = (float*)d_out;
  float* probs = out + OUT_ELEMS;

  const size_t NE = (size_t)B_ * H_ * L_ * HD_;   // 3145728
  unsigned short* qbw   = (unsigned short*)d_ws;  // bf16 q [B,H,L,64]
  unsigned short* kbw   = qbw + NE;
  unsigned short* vbw   = kbw + NE;
  unsigned short* vtw   = vbw + NE;               // v^T [B,H,64,L]
  unsigned short* xbw   = vtw + NE;               // bf16 x [M,K]
  unsigned short* attnb = xbw + NE;               // bf16 attn [B,L,D]
  unsigned short* wqT   = attnb + NE;             // bf16 w_qkv^T [2304,768]
  unsigned short* woT   = wqT + (size_t)N3_ * D_; // bf16 w_out^T [768,768]
  // total: 6*6.29MB + 3.54MB + 1.18MB = 42.5 MB

  // 1) conversions (independent)
  bf16conv_kernel<<<(int)(OUT_ELEMS / 8 / 256), 256, 0, stream>>>(x, xbw);
  wtrans_kernel<<<dim3(N3_ / 64, D_ / 64), 256, 0, stream>>>(w_qkv, wqT, D_, N3_);
  wtrans_kernel<<<dim3(D_ / 64, D_ / 64), 256, 0, stream>>>(w_out, woT, D_, D_);

  // 2) QKV projection (MFMA) + bias + fused RoPE + head-split -> bf16 q/k/v
  gemm_mfma_kernel<<<dim3(N3_ / 128, M_ / 128), 256, 0, stream>>>(
      xbw, wqT, b_qkv, nullptr, M_, N3_, D_, 1, qbw, kbw, vbw);

  // 3) V transpose for PV B-operand
  vtrans_kernel<<<dim3(L_ / 64, B_ * H_), 256, 0, stream>>>(vbw, vtw);

  // 4) fused causal attention: probs + attn (bf16)
  attn_mfma_kernel<<<dim3(L_ / 64, B_ * H_), 256, 0, stream>>>(qbw, kbw, vtw, probs, attnb);

  // 5) output projection (MFMA) + bias -> fp32 out
  gemm_mfma_kernel<<<dim3(D_ / 128, M_ / 128), 256, 0, stream>>>(
      attnb, woT, b_out, out, M_, D_, D_, 0, nullptr, nullptr, nullptr);
}